// Round 1
// 636.915 us; speedup vs baseline: 1.0416x; 1.0416x over previous
//
#include <hip/hip_runtime.h>

typedef __attribute__((ext_vector_type(8))) short short8;
typedef __attribute__((ext_vector_type(4))) float floatx4;

#define C_DIM 50000
#define D_DIM 1024
#define N_DIM 256
#define G_NUM 4
#define NNZ_G 300000
#define E_TOT (G_NUM * NNZ_G)

// workspace layout (bytes)
#define O_SB   0u                      // scale[1024] + bias[1024] fp32 = 8192
#define O_H0   8192u                   // h0 bf16 [256][1024] = 524288
#define O_ZT   532480u                 // Zt bf16 [50000][256] = 25600000
#define O_CNT  26132480u               // counts int[50000]
#define O_OFF  26332544u               // offsets int[50001]
#define O_CUR  26532608u               // cursor  int[50000]
#define O_BS   26732672u               // block sums int[256]
#define O_EDG  26733696u               // edges int2[1200000] = 9600000

static __device__ __forceinline__ unsigned short f2bf(float f) {
    union { float f; unsigned u; } v; v.f = f;
    unsigned r = v.u + 0x7fffu + ((v.u >> 16) & 1u);   // RNE
    return (unsigned short)(r >> 16);
}
static __device__ __forceinline__ float bf2f(unsigned short u) {
    union { unsigned u; float f; } v; v.u = ((unsigned)u) << 16;
    return v.f;
}

static __device__ __forceinline__ short8 cvt8(float4 a, float4 b) {
    short8 r;
    r[0] = (short)f2bf(a.x); r[1] = (short)f2bf(a.y);
    r[2] = (short)f2bf(a.z); r[3] = (short)f2bf(a.w);
    r[4] = (short)f2bf(b.x); r[5] = (short)f2bf(b.y);
    r[6] = (short)f2bf(b.z); r[7] = (short)f2bf(b.w);
    return r;
}

// ---- 1. BatchNorm stats
__global__ __launch_bounds__(256) void k_bnstats(const float* __restrict__ x,
                                                 float* __restrict__ scale,
                                                 float* __restrict__ bias) {
    int d = blockIdx.x * 256 + threadIdx.x;
    float s = 0.f, ss = 0.f;
    for (int n = 0; n < N_DIM; ++n) {
        float v = x[n * D_DIM + d];
        s += v; ss += v * v;
    }
    float mean = s * (1.f / N_DIM);
    float var  = ss * (1.f / N_DIM) - mean * mean;
    float sc = rsqrtf(var + 1e-5f);
    scale[d] = sc;
    bias[d] = -mean * sc;
}

// ---- 2. h0 = normalize(x) in bf16
__global__ __launch_bounds__(256) void k_h0(const float* __restrict__ x,
                                            const float* __restrict__ scale,
                                            const float* __restrict__ bias,
                                            unsigned short* __restrict__ h0) {
    int id = blockIdx.x * 256 + threadIdx.x;
    int d = id & (D_DIM - 1);
    h0[id] = f2bf(x[id] * scale[d] + bias[d]);
}

// ---- 3. GEMM: Zt[c][b] = swish(W@h0 + wb).
// Tile 64(C) x 256(N), BK=64, 4 waves; wave w owns N-chunk [w*64, w*64+64).
// A (W fp32 -> bf16) double-buffered in LDS, FRAGMENT-ORDERED so writer lane l
// stages reader lane l's data: ds_write_b128/ds_read_b128 both lane-contiguous
// => zero bank conflicts. B (h0) read directly from global (L2-hot, natural
// layout). One barrier per K-step; next-tile global loads issued before MFMA.
__global__ __launch_bounds__(256) void k_gemm(const float* __restrict__ W,
                                              const float* __restrict__ wb,
                                              const unsigned short* __restrict__ h0,
                                              unsigned short* __restrict__ Zt) {
    // [buf][plane p = kh*4 + i][lane][8 bf16]  -> 2 x 8 KiB
    __shared__ unsigned short A_lds[2][8 * 64 * 8];
    const int t = threadIdx.x;
    const int w = t >> 6, lane = t & 63;
    const int m = lane & 15, g = lane >> 4;
    const int c0 = blockIdx.x * 64;

    // staging: wave w stages planes p0=2w, p1=2w+1.
    // plane p, lane l holds W[c0 + (p&3)*16 + (l&15)][kk + (p>>2)*32 + (l>>4)*8 .. +8]
    const int p0 = 2 * w, p1 = 2 * w + 1;
    int r0s = c0 + (p0 & 3) * 16 + m; if (r0s >= C_DIM) r0s = C_DIM - 1;
    int r1s = c0 + (p1 & 3) * 16 + m; if (r1s >= C_DIM) r1s = C_DIM - 1;
    const float* srcA0 = &W[(size_t)r0s * D_DIM + (p0 >> 2) * 32 + g * 8];
    const float* srcA1 = &W[(size_t)r1s * D_DIM + (p1 >> 2) * 32 + g * 8];
    unsigned short* dst0base = &A_lds[0][0];

    const unsigned short* hb = h0 + (size_t)(w * 64 + m) * D_DIM;

    floatx4 acc[4][4];
#pragma unroll
    for (int i = 0; i < 4; ++i)
#pragma unroll
        for (int j = 0; j < 4; ++j) acc[i][j] = (floatx4)0.f;

    float4 pa0, pa1, pb0, pb1;   // staged next-tile W regs

#define LOADA(kkv)                                              \
    {                                                           \
        const float4* sa = (const float4*)(srcA0 + (kkv));      \
        const float4* sb = (const float4*)(srcA1 + (kkv));      \
        pa0 = sa[0]; pa1 = sa[1];                               \
        pb0 = sb[0]; pb1 = sb[1];                               \
    }
#define STOREA(bufv)                                                        \
    {                                                                       \
        *(short8*)&A_lds[(bufv)][p0 * 512 + lane * 8] = cvt8(pa0, pa1);     \
        *(short8*)&A_lds[(bufv)][p1 * 512 + lane * 8] = cvt8(pb0, pb1);     \
    }

    LOADA(0);
    STOREA(0);
    __syncthreads();

    int cur = 0;
#pragma unroll 1
    for (int ks = 0; ks < 16; ++ks) {
        const int kk = ks * 64;
        // B fragments straight from global (L1/L2-hot h0)
        short8 bfrag[2][4];
#pragma unroll
        for (int kh = 0; kh < 2; ++kh)
#pragma unroll
            for (int j = 0; j < 4; ++j)
                bfrag[kh][j] = *(const short8*)&hb[(size_t)(j * 16) * D_DIM + kk + kh * 32 + g * 8];

        // issue next A tile early (latency hides under ds_read + MFMA)
        if (ks < 15) LOADA(kk + 64);

        // A fragments: lane-contiguous, conflict-free
        short8 afrag[2][4];
#pragma unroll
        for (int kh = 0; kh < 2; ++kh)
#pragma unroll
            for (int i = 0; i < 4; ++i)
                afrag[kh][i] = *(const short8*)&A_lds[cur][(kh * 4 + i) * 512 + lane * 8];

        __builtin_amdgcn_s_setprio(1);
#pragma unroll
        for (int kh = 0; kh < 2; ++kh)
#pragma unroll
            for (int i = 0; i < 4; ++i)
#pragma unroll
                for (int j = 0; j < 4; ++j)
                    acc[i][j] = __builtin_amdgcn_mfma_f32_16x16x32_bf16(afrag[kh][i], bfrag[kh][j], acc[i][j], 0, 0, 0);
        __builtin_amdgcn_s_setprio(0);

        // convert + write next tile into the other buffer
        if (ks < 15) STOREA(cur ^ 1);
        __syncthreads();
        cur ^= 1;
    }
#undef LOADA
#undef STOREA

    // epilogue: bias + swish, store bf16 to Zt[c][b]
#pragma unroll
    for (int i = 0; i < 4; ++i) {
#pragma unroll
        for (int j = 0; j < 4; ++j) {
            int b = w * 64 + j * 16 + m;
#pragma unroll
            for (int rr = 0; rr < 4; ++rr) {
                int c = c0 + i * 16 + g * 4 + rr;
                if (c < C_DIM) {
                    float x = acc[i][j][rr] + wb[c];
                    float z = x / (1.f + __expf(-x));
                    Zt[(size_t)c * 256 + b] = f2bf(z);
                }
            }
        }
    }
    (void)dst0base;
}

// ---- 4. CSR build
__global__ __launch_bounds__(256) void k_count(const int* __restrict__ rows,
                                               int* __restrict__ counts) {
    int id = blockIdx.x * 256 + threadIdx.x;
    if (id < E_TOT) atomicAdd(&counts[rows[id]], 1);
}

__global__ __launch_bounds__(256) void k_scan1(const int* __restrict__ counts,
                                               int* __restrict__ offsets,
                                               int* __restrict__ bsums) {
    __shared__ int sm[256];
    int t = threadIdx.x, i = blockIdx.x * 256 + t;
    int v = (i < C_DIM) ? counts[i] : 0;
    sm[t] = v; __syncthreads();
    for (int off = 1; off < 256; off <<= 1) {
        int x = (t >= off) ? sm[t - off] : 0;
        __syncthreads();
        sm[t] += x;
        __syncthreads();
    }
    if (i < C_DIM) offsets[i] = sm[t] - v;
    if (t == 255) bsums[blockIdx.x] = sm[255];
}

__global__ __launch_bounds__(256) void k_scan2(int* __restrict__ bsums,
                                               int* __restrict__ offsets) {
    __shared__ int sm[256];
    int t = threadIdx.x;
    int v = (t < 196) ? bsums[t] : 0;
    sm[t] = v; __syncthreads();
    for (int off = 1; off < 256; off <<= 1) {
        int x = (t >= off) ? sm[t - off] : 0;
        __syncthreads();
        sm[t] += x;
        __syncthreads();
    }
    if (t < 196) bsums[t] = sm[t] - v;
    if (t == 0) offsets[C_DIM] = sm[255];
}

__global__ __launch_bounds__(256) void k_scan3(const int* __restrict__ bsums,
                                               int* __restrict__ offsets,
                                               int* __restrict__ cursor) {
    int i = blockIdx.x * 256 + threadIdx.x;
    if (i < C_DIM) {
        int off = offsets[i] + bsums[blockIdx.x];
        offsets[i] = off;
        cursor[i] = off;
    }
}

__global__ __launch_bounds__(256) void k_scatter(const int* __restrict__ rows,
                                                 const int* __restrict__ cols,
                                                 const float* __restrict__ vals,
                                                 const float* __restrict__ vec,
                                                 int* __restrict__ cursor,
                                                 int2* __restrict__ edges) {
    int id = blockIdx.x * 256 + threadIdx.x;
    if (id < E_TOT) {
        int gidx = id / NNZ_G;
        float v = vals[id] * vec[gidx];
        int r = rows[id];
        int c = cols[id];
        int pos = atomicAdd(&cursor[r], 1);
        edges[pos] = make_int2(c, __float_as_int(v));
    }
}

// ---- 5. Aggregation + residual. Block = 4 waves = 32 rows (wave: 8 rows seq).
__global__ __launch_bounds__(256) void k_agg(const unsigned short* __restrict__ Zt,
                                             const int* __restrict__ offsets,
                                             const int2* __restrict__ edges,
                                             float* __restrict__ out) {
    __shared__ float sm[32 * 256];
    const int t = threadIdx.x;
    const int w = t >> 6, lane = t & 63;
    const int r0 = blockIdx.x * 32;
    const int base = lane * 4;

#pragma unroll 1
    for (int k = 0; k < 8; ++k) {
        int lrow = w * 8 + k;
        int r = __builtin_amdgcn_readfirstlane(r0 + lrow);
        if (r < C_DIM) {
            ushort4 z = *(const ushort4*)&Zt[(size_t)r * 256 + base];
            float a0 = bf2f(z.x), a1 = bf2f(z.y), a2 = bf2f(z.z), a3 = bf2f(z.w);
            int s = offsets[r], e = offsets[r + 1];
            for (; s + 4 <= e; s += 4) {
                int2 e0 = edges[s], e1 = edges[s + 1], e2 = edges[s + 2], e3 = edges[s + 3];
                ushort4 g0 = *(const ushort4*)&Zt[(size_t)e0.x * 256 + base];
                ushort4 g1 = *(const ushort4*)&Zt[(size_t)e1.x * 256 + base];
                ushort4 g2 = *(const ushort4*)&Zt[(size_t)e2.x * 256 + base];
                ushort4 g3 = *(const ushort4*)&Zt[(size_t)e3.x * 256 + base];
                float v0 = __int_as_float(e0.y), v1 = __int_as_float(e1.y);
                float v2 = __int_as_float(e2.y), v3 = __int_as_float(e3.y);
                a0 += v0 * bf2f(g0.x) + v1 * bf2f(g1.x) + v2 * bf2f(g2.x) + v3 * bf2f(g3.x);
                a1 += v0 * bf2f(g0.y) + v1 * bf2f(g1.y) + v2 * bf2f(g2.y) + v3 * bf2f(g3.y);
                a2 += v0 * bf2f(g0.z) + v1 * bf2f(g1.z) + v2 * bf2f(g2.z) + v3 * bf2f(g3.z);
                a3 += v0 * bf2f(g0.w) + v1 * bf2f(g1.w) + v2 * bf2f(g2.w) + v3 * bf2f(g3.w);
            }
            for (; s < e; ++s) {
                int2 e0 = edges[s];
                ushort4 g0 = *(const ushort4*)&Zt[(size_t)e0.x * 256 + base];
                float v0 = __int_as_float(e0.y);
                a0 += v0 * bf2f(g0.x);
                a1 += v0 * bf2f(g0.y);
                a2 += v0 * bf2f(g0.z);
                a3 += v0 * bf2f(g0.w);
            }
            *(float4*)&sm[lrow * 256 + base] = make_float4(a0, a1, a2, a3);
        }
    }
    __syncthreads();

    int rows = C_DIM - r0; if (rows > 32) rows = 32;
    int nq = rows >> 2;
    float4* op = (float4*)&out[(size_t)t * C_DIM + r0];
#pragma unroll 1
    for (int q = 0; q < nq; ++q) {
        float4 o;
        o.x = sm[(q * 4 + 0) * 256 + t];
        o.y = sm[(q * 4 + 1) * 256 + t];
        o.z = sm[(q * 4 + 2) * 256 + t];
        o.w = sm[(q * 4 + 3) * 256 + t];
        op[q] = o;
    }
}

extern "C" void kernel_launch(void* const* d_in, const int* in_sizes, int n_in,
                              void* d_out, int out_size, void* d_ws, size_t ws_size,
                              hipStream_t stream) {
    (void)in_sizes; (void)n_in; (void)out_size; (void)ws_size;
    const float* x     = (const float*)d_in[0];
    const float* W     = (const float*)d_in[1];
    const float* wb    = (const float*)d_in[2];
    const float* Avals = (const float*)d_in[3];
    const float* vec   = (const float*)d_in[4];
    const int*   Arows = (const int*)d_in[5];
    const int*   Acols = (const int*)d_in[6];
    float* out = (float*)d_out;
    char* ws = (char*)d_ws;

    float* scale = (float*)(ws + O_SB);
    float* bias  = scale + 1024;
    unsigned short* h0 = (unsigned short*)(ws + O_H0);
    unsigned short* Zt = (unsigned short*)(ws + O_ZT);
    int* counts  = (int*)(ws + O_CNT);
    int* offsets = (int*)(ws + O_OFF);
    int* cursor  = (int*)(ws + O_CUR);
    int* bsums   = (int*)(ws + O_BS);
    int2* edges  = (int2*)(ws + O_EDG);

    hipMemsetAsync(counts, 0, C_DIM * sizeof(int), stream);

    k_bnstats<<<4, 256, 0, stream>>>(x, scale, bias);
    k_h0<<<1024, 256, 0, stream>>>(x, scale, bias, h0);
    k_count<<<(E_TOT + 255) / 256, 256, 0, stream>>>(Arows, counts);
    k_gemm<<<(C_DIM + 63) / 64, 256, 0, stream>>>(W, wb, h0, Zt);
    k_scan1<<<196, 256, 0, stream>>>(counts, offsets, bsums);
    k_scan2<<<1, 256, 0, stream>>>(bsums, offsets);
    k_scan3<<<196, 256, 0, stream>>>(bsums, offsets, cursor);
    k_scatter<<<(E_TOT + 255) / 256, 256, 0, stream>>>(Arows, Acols, Avals, vec, cursor, edges);
    k_agg<<<(C_DIM + 31) / 32, 256, 0, stream>>>(Zt, offsets, edges, out);
}

// Round 2
// 625.128 us; speedup vs baseline: 1.0612x; 1.0189x over previous
//
#include <hip/hip_runtime.h>

typedef __attribute__((ext_vector_type(8))) short short8;
typedef __attribute__((ext_vector_type(4))) float floatx4;

#define C_DIM 50000
#define D_DIM 1024
#define N_DIM 256
#define G_NUM 4
#define NNZ_G 300000
#define E_TOT (G_NUM * NNZ_G)

// workspace layout (bytes)
#define O_SB   0u                      // scale[1024] + bias[1024] fp32 = 8192
#define O_H0   8192u                   // h0F bf16 fragment-tiled, 524288 B
#define O_ZT   532480u                 // Zt bf16 [50000][256] = 25600000
#define O_CNT  26132480u               // counts int[50000]
#define O_OFF  26332544u               // offsets int[50001]
#define O_CUR  26532608u               // cursor  int[50000]
#define O_BS   26732672u               // block sums int[256]
#define O_EDG  26733696u               // edges int2[1200000] = 9600000

static __device__ __forceinline__ unsigned short f2bf(float f) {
    union { float f; unsigned u; } v; v.f = f;
    unsigned r = v.u + 0x7fffu + ((v.u >> 16) & 1u);   // RNE
    return (unsigned short)(r >> 16);
}
static __device__ __forceinline__ float bf2f(unsigned short u) {
    union { unsigned u; float f; } v; v.u = ((unsigned)u) << 16;
    return v.f;
}

// ---- 1. BatchNorm stats (32 blocks x 256: 8 n-groups x 32 d-cols each)
__global__ __launch_bounds__(256) void k_bnstats(const float* __restrict__ x,
                                                 float* __restrict__ scale,
                                                 float* __restrict__ bias) {
    __shared__ float sms[8][32], smss[8][32];
    const int t = threadIdx.x;
    const int dc = t & 31, grp = t >> 5;
    const int d = blockIdx.x * 32 + dc;
    float s = 0.f, ss = 0.f;
    for (int n = grp; n < N_DIM; n += 8) {
        float v = x[n * D_DIM + d];
        s += v; ss += v * v;
    }
    sms[grp][dc] = s; smss[grp][dc] = ss;
    __syncthreads();
    if (t < 32) {
        float S = 0.f, SS = 0.f;
#pragma unroll
        for (int g2 = 0; g2 < 8; ++g2) { S += sms[g2][t]; SS += smss[g2][t]; }
        float mean = S * (1.f / N_DIM);
        float var  = SS * (1.f / N_DIM) - mean * mean;
        float sc = rsqrtf(var + 1e-5f);
        int dd = blockIdx.x * 32 + t;
        scale[dd] = sc;
        bias[dd] = -mean * sc;
    }
}

// ---- 2. h0F = normalize(x), bf16, MFMA-B-fragment-tiled layout.
// chunk (b, kc) = 8 bf16 of h0[b][kc*8 .. +8] stored at ushort offset
//   (b>>4)*16384 + (kc>>2)*512 + (kc&3)*128 + (b&15)*8
// so a wave's B-frag load (w,j,ks,kh) is contiguous 1024 B: base + lane*16B.
__global__ __launch_bounds__(256) void k_h0f(const float* __restrict__ x,
                                             const float* __restrict__ scale,
                                             const float* __restrict__ bias,
                                             unsigned short* __restrict__ h0F) {
    int id = blockIdx.x * 256 + threadIdx.x;        // 32768 chunks
    int b = id >> 7, kc = id & 127;
    const float4* xp = (const float4*)&x[(size_t)b * D_DIM + kc * 8];
    float4 f0 = xp[0], f1 = xp[1];
    const float4* sp = (const float4*)&scale[kc * 8];
    const float4* bp = (const float4*)&bias[kc * 8];
    float4 s0 = sp[0], s1 = sp[1], b0 = bp[0], b1 = bp[1];
    short8 o;
    o[0] = (short)f2bf(f0.x * s0.x + b0.x);
    o[1] = (short)f2bf(f0.y * s0.y + b0.y);
    o[2] = (short)f2bf(f0.z * s0.z + b0.z);
    o[3] = (short)f2bf(f0.w * s0.w + b0.w);
    o[4] = (short)f2bf(f1.x * s1.x + b1.x);
    o[5] = (short)f2bf(f1.y * s1.y + b1.y);
    o[6] = (short)f2bf(f1.z * s1.z + b1.z);
    o[7] = (short)f2bf(f1.w * s1.w + b1.w);
    int off = (b >> 4) * 16384 + (kc >> 2) * 512 + (kc & 3) * 128 + (b & 15) * 8;
    *(short8*)&h0F[off] = o;
}

// ---- 3. GEMM: Zt[c][b] = swish(W@h0 + wb).
// 64(C) x 256(N) tile, BK=64, 4 waves. B straight from h0F (coalesced, L2-hot).
// A: coalesced global -> regs -> bf16 -> fragment-ordered LDS, double-buffered,
// W prefetch 2 tiles deep. Raw s_barrier (lgkm-only drain) keeps W loads in
// flight across barriers.
__global__ __launch_bounds__(256) void k_gemm(const float* __restrict__ W,
                                              const float* __restrict__ wb,
                                              const unsigned short* __restrict__ h0F,
                                              unsigned short* __restrict__ Zt) {
    __shared__ unsigned short A_lds[2][8 * 64 * 8];   // [buf][plane p=kh*4+i][lane][8]
    const int t = threadIdx.x;
    const int w = t >> 6, lane = t & 63;
    const int m = lane & 15, g = lane >> 4;
    const int c0 = blockIdx.x * 64;

    // A staging: instr q covers rows [q*16, q*16+16), thread -> row q*16+(t>>4),
    // col-chunk (t&15)*4 fp32. Per instr: 4x 256B contiguous segments.
    const int srow = t >> 4;
    const int scc  = t & 15;
    const int s_kh = scc >> 3;
    const int s_g  = (scc >> 1) & 3;
    const int s_half = scc & 1;
    const int sbase = (srow + 16 * s_g) * 8 + s_half * 4;   // ushort offset in plane

    const unsigned short* hb = h0F + (size_t)(w * 4) * 16384 + lane * 8;

    float4 raA[4], raB[4];
    floatx4 acc[4][4];
#pragma unroll
    for (int i = 0; i < 4; ++i)
#pragma unroll
        for (int j = 0; j < 4; ++j) acc[i][j] = (floatx4)0.f;

#define LOADA(RA, ksv)                                                           \
    {                                                                            \
        const int kkv = (ksv) * 64;                                              \
        _Pragma("unroll")                                                        \
        for (int q = 0; q < 4; ++q) {                                            \
            int rr_ = c0 + q * 16 + srow; if (rr_ >= C_DIM) rr_ = C_DIM - 1;     \
            RA[q] = *(const float4*)&W[(size_t)rr_ * D_DIM + kkv + scc * 4];     \
        }                                                                        \
    }
#define STOREA(RA, bufv)                                                          \
    {                                                                             \
        _Pragma("unroll")                                                         \
        for (int q = 0; q < 4; ++q) {                                             \
            float4 f_ = RA[q];                                                    \
            unsigned p0_ = (unsigned)f2bf(f_.x) | ((unsigned)f2bf(f_.y) << 16);   \
            unsigned p1_ = (unsigned)f2bf(f_.z) | ((unsigned)f2bf(f_.w) << 16);   \
            *(uint2*)&A_lds[bufv][(s_kh * 4 + q) * 512 + sbase] =                 \
                make_uint2(p0_, p1_);                                             \
        }                                                                         \
    }
#define BARRIER()                                               \
    asm volatile("s_waitcnt lgkmcnt(0)" ::: "memory");          \
    __builtin_amdgcn_sched_barrier(0);                          \
    __builtin_amdgcn_s_barrier();                               \
    __builtin_amdgcn_sched_barrier(0);

// one K-step: read buf CUR; store tile ks+1 (regset RAs) -> buf CUR^1;
// prefetch tile ks+2 -> regset RAl (stays in flight across the barrier).
#define GSTEP(ksv, RAs, RAl, CUR)                                                 \
    {                                                                             \
        short8 bfrag[2][4];                                                       \
        _Pragma("unroll")                                                         \
        for (int kh = 0; kh < 2; ++kh)                                            \
            _Pragma("unroll")                                                     \
            for (int j = 0; j < 4; ++j)                                           \
                bfrag[kh][j] = *(const short8*)&hb[(size_t)j * 16384 +            \
                                                  ((ksv) * 2 + kh) * 512];        \
        short8 afrag[2][4];                                                       \
        _Pragma("unroll")                                                         \
        for (int kh = 0; kh < 2; ++kh)                                            \
            _Pragma("unroll")                                                     \
            for (int i = 0; i < 4; ++i)                                           \
                afrag[kh][i] = *(const short8*)&A_lds[CUR][(kh * 4 + i) * 512 +   \
                                                          lane * 8];              \
        if ((ksv) < 15) STOREA(RAs, (CUR) ^ 1)                                    \
        if ((ksv) < 14) LOADA(RAl, (ksv) + 2)                                     \
        __builtin_amdgcn_s_setprio(1);                                            \
        _Pragma("unroll")                                                         \
        for (int kh = 0; kh < 2; ++kh)                                            \
            _Pragma("unroll")                                                     \
            for (int i = 0; i < 4; ++i)                                           \
                _Pragma("unroll")                                                 \
                for (int j = 0; j < 4; ++j)                                       \
                    acc[i][j] = __builtin_amdgcn_mfma_f32_16x16x32_bf16(          \
                        afrag[kh][i], bfrag[kh][j], acc[i][j], 0, 0, 0);          \
        __builtin_amdgcn_s_setprio(0);                                            \
        BARRIER()                                                                 \
    }

    // prologue: tile0 -> buf0 (via raA), tile1 in flight in raB
    LOADA(raA, 0)
    STOREA(raA, 0)
    LOADA(raB, 1)
    BARRIER()

#pragma unroll 1
    for (int ks2 = 0; ks2 < 16; ks2 += 2) {
        GSTEP(ks2,     raB, raA, 0)   // even step: store T(ks+1)=odd from raB, load T(ks+2) -> raA
        GSTEP(ks2 + 1, raA, raB, 1)   // odd step:  store from raA, load -> raB
    }
#undef GSTEP
#undef LOADA
#undef STOREA
#undef BARRIER

    // epilogue: bias + swish, store bf16 to Zt[c][b]
#pragma unroll
    for (int i = 0; i < 4; ++i) {
#pragma unroll
        for (int j = 0; j < 4; ++j) {
            int b = w * 64 + j * 16 + m;
#pragma unroll
            for (int rr = 0; rr < 4; ++rr) {
                int c = c0 + i * 16 + g * 4 + rr;
                if (c < C_DIM) {
                    float x = acc[i][j][rr] + wb[c];
                    float z = x / (1.f + __expf(-x));
                    Zt[(size_t)c * 256 + b] = f2bf(z);
                }
            }
        }
    }
}

// ---- 4. CSR build
__global__ __launch_bounds__(256) void k_count(const int* __restrict__ rows,
                                               int* __restrict__ counts) {
    int id = blockIdx.x * 256 + threadIdx.x;
    if (id < E_TOT) atomicAdd(&counts[rows[id]], 1);
}

__global__ __launch_bounds__(256) void k_scan1(const int* __restrict__ counts,
                                               int* __restrict__ offsets,
                                               int* __restrict__ bsums) {
    __shared__ int sm[256];
    int t = threadIdx.x, i = blockIdx.x * 256 + t;
    int v = (i < C_DIM) ? counts[i] : 0;
    sm[t] = v; __syncthreads();
    for (int off = 1; off < 256; off <<= 1) {
        int x = (t >= off) ? sm[t - off] : 0;
        __syncthreads();
        sm[t] += x;
        __syncthreads();
    }
    if (i < C_DIM) offsets[i] = sm[t] - v;
    if (t == 255) bsums[blockIdx.x] = sm[255];
}

__global__ __launch_bounds__(256) void k_scan2(int* __restrict__ bsums,
                                               int* __restrict__ offsets) {
    __shared__ int sm[256];
    int t = threadIdx.x;
    int v = (t < 196) ? bsums[t] : 0;
    sm[t] = v; __syncthreads();
    for (int off = 1; off < 256; off <<= 1) {
        int x = (t >= off) ? sm[t - off] : 0;
        __syncthreads();
        sm[t] += x;
        __syncthreads();
    }
    if (t < 196) bsums[t] = sm[t] - v;
    if (t == 0) offsets[C_DIM] = sm[255];
}

__global__ __launch_bounds__(256) void k_scan3(const int* __restrict__ bsums,
                                               int* __restrict__ offsets,
                                               int* __restrict__ cursor) {
    int i = blockIdx.x * 256 + threadIdx.x;
    if (i < C_DIM) {
        int off = offsets[i] + bsums[blockIdx.x];
        offsets[i] = off;
        cursor[i] = off;
    }
}

__global__ __launch_bounds__(256) void k_scatter(const int* __restrict__ rows,
                                                 const int* __restrict__ cols,
                                                 const float* __restrict__ vals,
                                                 const float* __restrict__ vec,
                                                 int* __restrict__ cursor,
                                                 int2* __restrict__ edges) {
    int id = blockIdx.x * 256 + threadIdx.x;
    if (id < E_TOT) {
        int gidx = id / NNZ_G;
        float v = vals[id] * vec[gidx];
        int r = rows[id];
        int c = cols[id];
        int pos = atomicAdd(&cursor[r], 1);
        edges[pos] = make_int2(c, __float_as_int(v));
    }
}

// ---- 5. Aggregation + residual. Block = 4 waves = 32 rows (wave: 8 rows seq).
// 2 edges per wave instruction (32 lanes x 16B each), 4 edges in flight,
// cross-half combine via shfl_xor(32).
__global__ __launch_bounds__(256) void k_agg(const unsigned short* __restrict__ Zt,
                                             const int* __restrict__ offsets,
                                             const int2* __restrict__ edges,
                                             float* __restrict__ out) {
    __shared__ float sm[32 * 256];
    const int t = threadIdx.x;
    const int w = t >> 6, lane = t & 63;
    const int r0 = blockIdx.x * 32;
    const int h = lane & 31;          // col chunk: cols [h*8, h*8+8)
    const int eh = lane >> 5;         // which edge of the pair
    const int base = h * 8;

#pragma unroll 1
    for (int k = 0; k < 8; ++k) {
        int lrow = w * 8 + k;
        int r = __builtin_amdgcn_readfirstlane(r0 + lrow);
        if (r < C_DIM) {
            float a[8];
            {   // residual Z: only half 0 contributes (half 1 added via combine)
                short8 z = *(const short8*)&Zt[(size_t)r * 256 + base];
                float zm = eh ? 0.f : 1.f;
#pragma unroll
                for (int j = 0; j < 8; ++j) a[j] = zm * bf2f((unsigned short)z[j]);
            }
            int s = offsets[r], e = offsets[r + 1];
            for (; s + 4 <= e; s += 4) {
                int2 ea = edges[s + eh];
                int2 eb = edges[s + 2 + eh];
                short8 ga = *(const short8*)&Zt[(size_t)(unsigned)ea.x * 256 + base];
                short8 gb = *(const short8*)&Zt[(size_t)(unsigned)eb.x * 256 + base];
                float va = __int_as_float(ea.y), vb = __int_as_float(eb.y);
#pragma unroll
                for (int j = 0; j < 8; ++j)
                    a[j] += va * bf2f((unsigned short)ga[j]) + vb * bf2f((unsigned short)gb[j]);
            }
            for (; s + 2 <= e; s += 2) {
                int2 ea = edges[s + eh];
                short8 ga = *(const short8*)&Zt[(size_t)(unsigned)ea.x * 256 + base];
                float va = __int_as_float(ea.y);
#pragma unroll
                for (int j = 0; j < 8; ++j)
                    a[j] += va * bf2f((unsigned short)ga[j]);
            }
            if (s < e) {   // single tail edge: half 1 contributes 0
                int2 e0 = edges[s];
                short8 g0 = *(const short8*)&Zt[(size_t)(unsigned)e0.x * 256 + base];
                float v0 = eh ? 0.f : __int_as_float(e0.y);
#pragma unroll
                for (int j = 0; j < 8; ++j)
                    a[j] += v0 * bf2f((unsigned short)g0[j]);
            }
#pragma unroll
            for (int j = 0; j < 8; ++j) a[j] += __shfl_xor(a[j], 32);
            if (eh == 0) {
                *(float4*)&sm[lrow * 256 + base]     = make_float4(a[0], a[1], a[2], a[3]);
                *(float4*)&sm[lrow * 256 + base + 4] = make_float4(a[4], a[5], a[6], a[7]);
            }
        }
    }
    __syncthreads();

    int rows = C_DIM - r0; if (rows > 32) rows = 32;
    int nq = rows >> 2;
    float4* op = (float4*)&out[(size_t)t * C_DIM + r0];
#pragma unroll 1
    for (int q = 0; q < nq; ++q) {
        float4 o;
        o.x = sm[(q * 4 + 0) * 256 + t];
        o.y = sm[(q * 4 + 1) * 256 + t];
        o.z = sm[(q * 4 + 2) * 256 + t];
        o.w = sm[(q * 4 + 3) * 256 + t];
        op[q] = o;
    }
}

extern "C" void kernel_launch(void* const* d_in, const int* in_sizes, int n_in,
                              void* d_out, int out_size, void* d_ws, size_t ws_size,
                              hipStream_t stream) {
    (void)in_sizes; (void)n_in; (void)out_size; (void)ws_size;
    const float* x     = (const float*)d_in[0];
    const float* W     = (const float*)d_in[1];
    const float* wb    = (const float*)d_in[2];
    const float* Avals = (const float*)d_in[3];
    const float* vec   = (const float*)d_in[4];
    const int*   Arows = (const int*)d_in[5];
    const int*   Acols = (const int*)d_in[6];
    float* out = (float*)d_out;
    char* ws = (char*)d_ws;

    float* scale = (float*)(ws + O_SB);
    float* bias  = scale + 1024;
    unsigned short* h0F = (unsigned short*)(ws + O_H0);
    unsigned short* Zt  = (unsigned short*)(ws + O_ZT);
    int* counts  = (int*)(ws + O_CNT);
    int* offsets = (int*)(ws + O_OFF);
    int* cursor  = (int*)(ws + O_CUR);
    int* bsums   = (int*)(ws + O_BS);
    int2* edges  = (int2*)(ws + O_EDG);

    hipMemsetAsync(counts, 0, C_DIM * sizeof(int), stream);

    k_bnstats<<<32, 256, 0, stream>>>(x, scale, bias);
    k_h0f<<<128, 256, 0, stream>>>(x, scale, bias, h0F);
    k_count<<<(E_TOT + 255) / 256, 256, 0, stream>>>(Arows, counts);
    k_gemm<<<(C_DIM + 63) / 64, 256, 0, stream>>>(W, wb, h0F, Zt);
    k_scan1<<<196, 256, 0, stream>>>(counts, offsets, bsums);
    k_scan2<<<1, 256, 0, stream>>>(bsums, offsets);
    k_scan3<<<196, 256, 0, stream>>>(bsums, offsets, cursor);
    k_scatter<<<(E_TOT + 255) / 256, 256, 0, stream>>>(Arows, Acols, Avals, vec, cursor, edges);
    k_agg<<<(C_DIM + 31) / 32, 256, 0, stream>>>(Zt, offsets, edges, out);
}